// Round 9
// baseline (306.793 us; speedup 1.0000x reference)
//
#include <hip/hip_runtime.h>
#include <math.h>

#define N_HALF 4096
#define D 64
#define M_TOT 8192
#define NPAIR 2080  // 64*65/2 upper-triangle 128x128 tile pairs

typedef short short8_t __attribute__((ext_vector_type(8)));
typedef unsigned short us8 __attribute__((ext_vector_type(8)));
typedef float f32x4 __attribute__((ext_vector_type(4)));

// Device-global scratch (fully rewritten by plain stores every call).
// Counters are static-zero and self-restored to 0 by the last user each
// call -> deterministic across graph replays, no static guards.
__device__ unsigned short Fhi[M_TOT * D];  // 1 MB fragment-major bf16 hi
__device__ unsigned short Flo[M_TOT * D];  // 1 MB bf16 lo residue
__device__ float g_norms[M_TOT];
__device__ float g_pssq[256];      // per-prep-block sum-of-squares partials
__device__ float g_pcol[256 * D];  // per-prep-block column-sum partials [b][c]
__device__ float g_coef;           // base exp2 coefficient g0
__device__ double g_part[NPAIR];   // per-pair signed partial sums
__device__ int g_cnt_prep;
__device__ int g_cnt_main;

static __device__ inline unsigned short f2bf(float x) {
    union { float f; unsigned u; } v; v.f = x;
    unsigned r = v.u + 0x7fff + ((v.u >> 16) & 1);  // RNE
    return (unsigned short)(r >> 16);
}
static __device__ inline float bf2f(unsigned short h) {
    union { unsigned u; float f; } v; v.u = ((unsigned)h) << 16;
    return v.f;
}

// Prep: split-bf16 convert to fragment-major + row norms + block partials;
// the LAST prep block additionally reduces the partials to the bandwidth
// coefficient (fused, saves a kernel node).
// F[rt][s][lane][e] = X[rt*16 + (lane&15)][s*32 + (lane>>4)*8 + e]
__global__ __launch_bounds__(256) void mmd_prep(const float* __restrict__ src,
                                                const float* __restrict__ tgt) {
    __shared__ float cs[D];
    __shared__ float hn[4][16];
    __shared__ int s_last;
    int t = threadIdx.x;
    if (t < D) cs[t] = 0.f;
    __syncthreads();
    int tid = blockIdx.x * 256 + t;  // 65536 threads total
    int l = tid & 63;
    int rs = tid >> 6;
    int s = rs & 1, rt = rs >> 1;
    int row = rt * 16 + (l & 15);
    int k0 = s * 32 + (l >> 4) * 8;
    const float* X = (row < N_HALF) ? src + (size_t)row * D
                                    : tgt + (size_t)(row - N_HALF) * D;
    float4 v0 = ((const float4*)(X + k0))[0];
    float4 v1 = ((const float4*)(X + k0))[1];
    float vs[8] = {v0.x, v0.y, v0.z, v0.w, v1.x, v1.y, v1.z, v1.w};
    us8 h, o;
    float p = 0.f;
#pragma unroll
    for (int e = 0; e < 8; ++e) {
        unsigned short hi = f2bf(vs[e]);
        h[e] = hi;
        o[e] = f2bf(vs[e] - bf2f(hi));
        p += vs[e] * vs[e];
    }
    ((us8*)Fhi)[tid] = h;
    ((us8*)Flo)[tid] = o;
#pragma unroll
    for (int e = 0; e < 8; ++e) atomicAdd(&cs[k0 + e], vs[e]);  // LDS only
    p += __shfl_down(p, 32, 64);
    p += __shfl_down(p, 16, 64);
    int w = t >> 6;
    if (l < 16) hn[w][l] = p;
    __syncthreads();
    if (t < 64) {
        float nr = 0.f;
        int tile = t >> 4, r = t & 15;
        if (t < 32) {
            nr = hn[tile * 2][r] + hn[tile * 2 + 1][r];
            g_norms[(blockIdx.x * 2 + tile) * 16 + r] = nr;
        }
        nr += __shfl_down(nr, 32, 64);
        nr += __shfl_down(nr, 16, 64);
        nr += __shfl_down(nr, 8, 64);
        nr += __shfl_down(nr, 4, 64);
        nr += __shfl_down(nr, 2, 64);
        nr += __shfl_down(nr, 1, 64);
        if (t == 0) g_pssq[blockIdx.x] = nr;
    }
    if (t < D) g_pcol[blockIdx.x * D + t] = cs[t];

    // ---- last-block tail: bandwidth coefficient ----
    __threadfence();
    __syncthreads();
    if (t == 0) s_last = (atomicAdd(&g_cnt_prep, 1) == 255) ? 1 : 0;
    __syncthreads();
    if (s_last) {
        __threadfence();
        __shared__ float scol[4][64];
        __shared__ float sssq[4];
        float csum = 0.f;
#pragma unroll 16
        for (int q = 0; q < 64; ++q) csum += g_pcol[(w * 64 + q) * 64 + l];
        float sq = g_pssq[w * 64 + l];
#pragma unroll
        for (int off = 32; off; off >>= 1) sq += __shfl_xor(sq, off, 64);
        scol[w][l] = csum;
        if (l == 0) sssq[w] = sq;
        __syncthreads();
        if (t < 64) {
            float colsum = (scol[0][l] + scol[1][l]) + (scol[2][l] + scol[3][l]);
            float s2 = colsum * colsum;
#pragma unroll
            for (int off = 32; off; off >>= 1) s2 += __shfl_xor(s2, off, 64);
            if (t == 0) {
                float ssq = (sssq[0] + sssq[1]) + (sssq[2] + sssq[3]);
                const float M = (float)M_TOT;
                float sumL2 = 2.f * M * ssq - 2.f * s2;
                float bwq = sumL2 / (M * M - M) * 0.25f;
                g_coef = -1.4426950408889634f / (bwq * 16.f);
                atomicExch(&g_cnt_prep, 0);  // restore for next call
            }
        }
    }
}

static __device__ inline void decode_pair(int id, int& bi, int& bj) {
    bi = (int)(64.5f - sqrtf(4160.25f - 2.0f * (float)id));
    while ((64 * (bi + 1) - ((bi + 1) * bi) / 2) <= id) ++bi;
    while ((64 * bi - (bi * (bi - 1)) / 2) > id) --bi;
    bj = bi + (id - (64 * bi - (bi * (bi - 1)) / 2));
}

// Main: one 128x128 pair tile per block, 8 waves of 64x32 each.
// Epilogue per output uses 3 INDEPENDENT exp2 (t0, 4t0, 16t0) + 2 fma
// squarings (k3=k4^2, k1=k2^2) and tree accumulation -> critical path
// ~exp+2 ops instead of exp + 4 serial muls + 32-long serial add chain.
// Last block reduces g_part and writes the output (fused, saves a node).
__global__ __launch_bounds__(512) void mmd_main(float* __restrict__ out) {
    __shared__ float sred[8];
    __shared__ int s_last;
    int t = threadIdx.x, w = t >> 6, l = t & 63;
    int wr = w >> 2, wc = w & 3;  // 2x4 wave grid: 64 rows x 32 cols per wave
    float g0 = g_coef;
    float c2 = -2.f * g0;
    const short8_t* FH = (const short8_t*)Fhi;
    const short8_t* FL = (const short8_t*)Flo;

    int bi, bj;
    decode_pair(blockIdx.x, bi, bj);

    // Norm loads issued early (consumed in epilogue).
    float nas[4][4];
#pragma unroll
    for (int m = 0; m < 4; ++m) {
        float4 v = *(const float4*)&g_norms[bi * 128 + wr * 64 + m * 16 + (l >> 4) * 4];
        nas[m][0] = v.x * g0; nas[m][1] = v.y * g0;
        nas[m][2] = v.z * g0; nas[m][3] = v.w * g0;
    }
    float nbv[2];
#pragma unroll
    for (int n = 0; n < 2; ++n)
        nbv[n] = g_norms[bj * 128 + wc * 32 + n * 16 + (l & 15)] * g0;

    f32x4 acc[4][2] = {};
#pragma unroll
    for (int s = 0; s < 2; ++s) {
        short8_t bh[2];
#pragma unroll
        for (int n = 0; n < 2; ++n)
            bh[n] = FH[((bj * 8 + wc * 2 + n) * 2 + s) * 64 + l];
#pragma unroll
        for (int m = 0; m < 4; ++m) {
            int fi = ((bi * 8 + wr * 4 + m) * 2 + s) * 64 + l;
            short8_t ah = FH[fi];
            short8_t al = FL[fi];
#pragma unroll
            for (int n = 0; n < 2; ++n) {
                acc[m][n] = __builtin_amdgcn_mfma_f32_16x16x32_bf16(al, bh[n], acc[m][n], 0, 0, 0);
                acc[m][n] = __builtin_amdgcn_mfma_f32_16x16x32_bf16(ah, bh[n], acc[m][n], 0, 0, 0);
            }
        }
    }

    // Epilogue: K_sum = e1 + e1^2 + e2 + e2^2 + e3 with e1=2^t0, e2=2^4t0,
    // e3=2^16t0 (k4,k3,k2,k1,k0). Tree-accumulated.
    float part8[8];
#pragma unroll
    for (int m = 0; m < 4; ++m)
#pragma unroll
        for (int n = 0; n < 2; ++n) {
            float og[4];
#pragma unroll
            for (int r = 0; r < 4; ++r) {
                float t0 = fmaf(acc[m][n][r], c2, nas[m][r] + nbv[n]);
                float e1 = __builtin_amdgcn_exp2f(t0);
                float e2 = __builtin_amdgcn_exp2f(t0 * 4.f);
                float e3 = __builtin_amdgcn_exp2f(t0 * 16.f);
                og[r] = (fmaf(e1, e1, e1) + fmaf(e2, e2, e2)) + e3;
            }
            part8[m * 2 + n] = (og[0] + og[1]) + (og[2] + og[3]);
        }
    float part = ((part8[0] + part8[1]) + (part8[2] + part8[3])) +
                 ((part8[4] + part8[5]) + (part8[6] + part8[7]));

#pragma unroll
    for (int off = 32; off; off >>= 1) part += __shfl_down(part, off, 64);
    if (l == 0) sred[w] = part;
    __syncthreads();
    if (t == 0) {
        float tot = ((sred[0] + sred[1]) + (sred[2] + sred[3])) +
                    ((sred[4] + sred[5]) + (sred[6] + sred[7]));
        float sgn = ((bi < 32) == (bj < 32)) ? 1.f : -1.f;
        float scl = (bi == bj) ? 1.f : 2.f;
        g_part[blockIdx.x] = (double)tot * (double)(sgn * scl);
    }

    // ---- last-block tail: deterministic reduce + output write ----
    __threadfence();
    __syncthreads();
    if (t == 0) s_last = (atomicAdd(&g_cnt_main, 1) == NPAIR - 1) ? 1 : 0;
    __syncthreads();
    if (s_last) {
        __threadfence();
        __shared__ double wred[8];
        double s = 0.0;
        for (int i = t; i < NPAIR; i += 512) s += g_part[i];
#pragma unroll
        for (int off = 32; off; off >>= 1) s += __shfl_down(s, off, 64);
        if (l == 0) wred[w] = s;
        __syncthreads();
        if (t == 0) {
            double tot = ((wred[0] + wred[1]) + (wred[2] + wred[3])) +
                         ((wred[4] + wred[5]) + (wred[6] + wred[7]));
            out[0] = (float)(tot * (1.0 / 16777216.0));  // / 4096^2
            atomicExch(&g_cnt_main, 0);  // restore for next call
        }
    }
}

extern "C" void kernel_launch(void* const* d_in, const int* in_sizes, int n_in,
                              void* d_out, int out_size, void* d_ws, size_t ws_size,
                              hipStream_t stream) {
    const float* src = (const float*)d_in[0];
    const float* tgt = (const float*)d_in[1];
    float* out = (float*)d_out;

    mmd_prep<<<256, 256, 0, stream>>>(src, tgt);
    mmd_main<<<NPAIR, 512, 0, stream>>>(out);
}

// Round 10
// 44.521 us; speedup vs baseline: 6.8909x; 6.8909x over previous
//
#include <hip/hip_runtime.h>
#include <math.h>

#define N_HALF 4096
#define D 64
#define M_TOT 8192
#define NPAIR 2080  // 64*65/2 upper-triangle 128x128 tile pairs

typedef short short8_t __attribute__((ext_vector_type(8)));
typedef unsigned short us8 __attribute__((ext_vector_type(8)));
typedef float f32x4 __attribute__((ext_vector_type(4)));

// Device-global scratch (fully rewritten by plain stores every call).
// NOTE (R9 lesson): NO per-block __threadfence / global ticket counters --
// device-scope fences force an XCD-L2 writeback and serialize the machine.
__device__ unsigned short Fhi[M_TOT * D];  // 1 MB fragment-major bf16 hi
__device__ unsigned short Flo[M_TOT * D];  // 1 MB bf16 lo residue
__device__ float g_norms[M_TOT];
__device__ float g_pssq[256];      // per-prep-block sum-of-squares partials
__device__ float g_pcol[256 * D];  // per-prep-block column-sum partials [b][c]
__device__ float g_coef;           // base exp2 coefficient g0
__device__ double g_part[NPAIR];   // per-pair signed partial sums

static __device__ inline unsigned short f2bf(float x) {
    union { float f; unsigned u; } v; v.f = x;
    unsigned r = v.u + 0x7fff + ((v.u >> 16) & 1);  // RNE
    return (unsigned short)(r >> 16);
}
static __device__ inline float bf2f(unsigned short h) {
    union { unsigned u; float f; } v; v.u = ((unsigned)h) << 16;
    return v.f;
}

// Prep: split-bf16 convert to fragment-major + row norms + block partials.
// F[rt][s][lane][e] = X[rt*16 + (lane&15)][s*32 + (lane>>4)*8 + e]
__global__ __launch_bounds__(256) void mmd_prep(const float* __restrict__ src,
                                                const float* __restrict__ tgt) {
    __shared__ float cs[D];
    __shared__ float hn[4][16];
    int t = threadIdx.x;
    if (t < D) cs[t] = 0.f;
    __syncthreads();
    int tid = blockIdx.x * 256 + t;  // 65536 threads total
    int l = tid & 63;
    int rs = tid >> 6;
    int s = rs & 1, rt = rs >> 1;
    int row = rt * 16 + (l & 15);
    int k0 = s * 32 + (l >> 4) * 8;
    const float* X = (row < N_HALF) ? src + (size_t)row * D
                                    : tgt + (size_t)(row - N_HALF) * D;
    float4 v0 = ((const float4*)(X + k0))[0];
    float4 v1 = ((const float4*)(X + k0))[1];
    float vs[8] = {v0.x, v0.y, v0.z, v0.w, v1.x, v1.y, v1.z, v1.w};
    us8 h, o;
    float p = 0.f;
#pragma unroll
    for (int e = 0; e < 8; ++e) {
        unsigned short hi = f2bf(vs[e]);
        h[e] = hi;
        o[e] = f2bf(vs[e] - bf2f(hi));
        p += vs[e] * vs[e];
    }
    ((us8*)Fhi)[tid] = h;
    ((us8*)Flo)[tid] = o;
#pragma unroll
    for (int e = 0; e < 8; ++e) atomicAdd(&cs[k0 + e], vs[e]);  // LDS only
    p += __shfl_down(p, 32, 64);
    p += __shfl_down(p, 16, 64);
    int w = t >> 6;
    if (l < 16) hn[w][l] = p;
    __syncthreads();
    if (t < 64) {
        float nr = 0.f;
        int tile = t >> 4, r = t & 15;
        if (t < 32) {
            nr = hn[tile * 2][r] + hn[tile * 2 + 1][r];
            g_norms[(blockIdx.x * 2 + tile) * 16 + r] = nr;
        }
        nr += __shfl_down(nr, 32, 64);
        nr += __shfl_down(nr, 16, 64);
        nr += __shfl_down(nr, 8, 64);
        nr += __shfl_down(nr, 4, 64);
        nr += __shfl_down(nr, 2, 64);
        nr += __shfl_down(nr, 1, 64);
        if (t == 0) g_pssq[blockIdx.x] = nr;
    }
    if (t < D) g_pcol[blockIdx.x * D + t] = cs[t];
}

// Bandwidth coefficient, one small block.
__global__ __launch_bounds__(256) void mmd_bw() {
    __shared__ float scol[4][64];
    __shared__ float sssq[4];
    int t = threadIdx.x, w = t >> 6, l = t & 63;
    float csum = 0.f;
#pragma unroll 16
    for (int q = 0; q < 64; ++q) csum += g_pcol[(w * 64 + q) * 64 + l];
    float sq = g_pssq[w * 64 + l];
#pragma unroll
    for (int off = 32; off; off >>= 1) sq += __shfl_xor(sq, off, 64);
    scol[w][l] = csum;
    if (l == 0) sssq[w] = sq;
    __syncthreads();
    if (t < 64) {
        float colsum = (scol[0][l] + scol[1][l]) + (scol[2][l] + scol[3][l]);
        float s2 = colsum * colsum;
#pragma unroll
        for (int off = 32; off; off >>= 1) s2 += __shfl_xor(s2, off, 64);
        if (t == 0) {
            float ssq = (sssq[0] + sssq[1]) + (sssq[2] + sssq[3]);
            const float M = (float)M_TOT;
            float sumL2 = 2.f * M * ssq - 2.f * s2;
            float bwq = sumL2 / (M * M - M) * 0.25f;
            g_coef = -1.4426950408889634f / (bwq * 16.f);
        }
    }
}

static __device__ inline void decode_pair(int id, int& bi, int& bj) {
    bi = (int)(64.5f - sqrtf(4160.25f - 2.0f * (float)id));
    while ((64 * (bi + 1) - ((bi + 1) * bi) / 2) <= id) ++bi;
    while ((64 * bi - (bi * (bi - 1)) / 2) > id) --bi;
    bj = bi + (id - (64 * bi - (bi * (bi - 1)) / 2));
}

// Main: one 128x128 pair tile per block, 8 waves of 64x32 each.
// acc[4][2] (32 AGPRs) keeps residency high (R8). Epilogue per output:
// 3 INDEPENDENT exp2 (t0, 4t0, 16t0) + 2 fma squarings + tree accumulation
// -> critical path ~exp+2 ops instead of exp + 4 serial muls + serial adds.
__global__ __launch_bounds__(512) void mmd_main() {
    __shared__ float sred[8];
    int t = threadIdx.x, w = t >> 6, l = t & 63;
    int wr = w >> 2, wc = w & 3;  // 2x4 wave grid: 64 rows x 32 cols per wave
    float g0 = g_coef;
    float c2 = -2.f * g0;
    const short8_t* FH = (const short8_t*)Fhi;
    const short8_t* FL = (const short8_t*)Flo;

    int bi, bj;
    decode_pair(blockIdx.x, bi, bj);

    // Norm loads issued early (consumed in epilogue).
    float nas[4][4];
#pragma unroll
    for (int m = 0; m < 4; ++m) {
        float4 v = *(const float4*)&g_norms[bi * 128 + wr * 64 + m * 16 + (l >> 4) * 4];
        nas[m][0] = v.x * g0; nas[m][1] = v.y * g0;
        nas[m][2] = v.z * g0; nas[m][3] = v.w * g0;
    }
    float nbv[2];
#pragma unroll
    for (int n = 0; n < 2; ++n)
        nbv[n] = g_norms[bj * 128 + wc * 32 + n * 16 + (l & 15)] * g0;

    f32x4 acc[4][2] = {};
#pragma unroll
    for (int s = 0; s < 2; ++s) {
        short8_t bh[2];
#pragma unroll
        for (int n = 0; n < 2; ++n)
            bh[n] = FH[((bj * 8 + wc * 2 + n) * 2 + s) * 64 + l];
#pragma unroll
        for (int m = 0; m < 4; ++m) {
            int fi = ((bi * 8 + wr * 4 + m) * 2 + s) * 64 + l;
            short8_t ah = FH[fi];
            short8_t al = FL[fi];
#pragma unroll
            for (int n = 0; n < 2; ++n) {
                acc[m][n] = __builtin_amdgcn_mfma_f32_16x16x32_bf16(al, bh[n], acc[m][n], 0, 0, 0);
                acc[m][n] = __builtin_amdgcn_mfma_f32_16x16x32_bf16(ah, bh[n], acc[m][n], 0, 0, 0);
            }
        }
    }

    // Epilogue: K_sum = e1 + e1^2 + e2 + e2^2 + e3, e1=2^t0, e2=2^4t0, e3=2^16t0.
    float part8[8];
#pragma unroll
    for (int m = 0; m < 4; ++m)
#pragma unroll
        for (int n = 0; n < 2; ++n) {
            float og[4];
#pragma unroll
            for (int r = 0; r < 4; ++r) {
                float t0 = fmaf(acc[m][n][r], c2, nas[m][r] + nbv[n]);
                float e1 = __builtin_amdgcn_exp2f(t0);
                float e2 = __builtin_amdgcn_exp2f(t0 * 4.f);
                float e3 = __builtin_amdgcn_exp2f(t0 * 16.f);
                og[r] = (fmaf(e1, e1, e1) + fmaf(e2, e2, e2)) + e3;
            }
            part8[m * 2 + n] = (og[0] + og[1]) + (og[2] + og[3]);
        }
    float part = ((part8[0] + part8[1]) + (part8[2] + part8[3])) +
                 ((part8[4] + part8[5]) + (part8[6] + part8[7]));

#pragma unroll
    for (int off = 32; off; off >>= 1) part += __shfl_down(part, off, 64);
    if (l == 0) sred[w] = part;
    __syncthreads();
    if (t == 0) {
        float tot = ((sred[0] + sred[1]) + (sred[2] + sred[3])) +
                    ((sred[4] + sred[5]) + (sred[6] + sred[7]));
        float sgn = ((bi < 32) == (bj < 32)) ? 1.f : -1.f;
        float scl = (bi == bj) ? 1.f : 2.f;
        g_part[blockIdx.x] = (double)tot * (double)(sgn * scl);
    }
}

// Deterministic tree reduce of the 2080 per-pair doubles.
__global__ __launch_bounds__(256) void mmd_out(float* __restrict__ out) {
    __shared__ double wred[4];
    int t = threadIdx.x;
    double s = 0.0;
    for (int i = t; i < NPAIR; i += 256) s += g_part[i];
#pragma unroll
    for (int off = 32; off; off >>= 1) s += __shfl_down(s, off, 64);
    if ((t & 63) == 0) wred[t >> 6] = s;
    __syncthreads();
    if (t == 0)
        out[0] = (float)((wred[0] + wred[1] + wred[2] + wred[3]) * (1.0 / 16777216.0));
}

extern "C" void kernel_launch(void* const* d_in, const int* in_sizes, int n_in,
                              void* d_out, int out_size, void* d_ws, size_t ws_size,
                              hipStream_t stream) {
    const float* src = (const float*)d_in[0];
    const float* tgt = (const float*)d_in[1];
    float* out = (float*)d_out;

    mmd_prep<<<256, 256, 0, stream>>>(src, tgt);
    mmd_bw<<<1, 256, 0, stream>>>();
    mmd_main<<<NPAIR, 512, 0, stream>>>();
    mmd_out<<<1, 256, 0, stream>>>(out);
}

// Round 11
// 35.132 us; speedup vs baseline: 8.7325x; 1.2672x over previous
//
#include <hip/hip_runtime.h>
#include <math.h>

#define N_HALF 4096
#define D 64
#define M_TOT 8192
#define NPAIR 2080  // 64*65/2 upper-triangle 128x128 tile pairs

typedef _Float16 half8 __attribute__((ext_vector_type(8)));
typedef float f32x4 __attribute__((ext_vector_type(4)));

// Device-global scratch (fully rewritten by plain stores every call).
// R9 lesson: no per-block device fences / ticket counters (XCD-L2 writeback
// serializes the machine). Separate tiny kernels handle cross-block deps.
__device__ _Float16 Fh[M_TOT * D];  // 1 MB fragment-major fp16 data
__device__ float g_norms[M_TOT];    // exact fp32 row norms
__device__ float g_pssq[256];       // per-prep-block sum-of-squares partials
__device__ float g_pcol[256 * D];   // per-prep-block column-sum partials
__device__ float g_coef;            // base exp2 coefficient g0
__device__ double g_part[NPAIR];    // per-pair signed partial sums

// Prep: fp16 convert into MFMA fragment-major layout + exact fp32 row norms
// + block partials for the bandwidth. F[rt][s][lane][e] =
// X[rt*16 + (lane&15)][s*32 + (lane>>4)*8 + e]  (same bijection for A and B
// operands -> dot products correct for any intra-MFMA k-order).
__global__ __launch_bounds__(256) void mmd_prep(const float* __restrict__ src,
                                                const float* __restrict__ tgt) {
    __shared__ float cs[D];
    __shared__ float hn[4][16];
    int t = threadIdx.x;
    if (t < D) cs[t] = 0.f;
    __syncthreads();
    int tid = blockIdx.x * 256 + t;  // 65536 threads total
    int l = tid & 63;
    int rs = tid >> 6;
    int s = rs & 1, rt = rs >> 1;
    int row = rt * 16 + (l & 15);
    int k0 = s * 32 + (l >> 4) * 8;
    const float* X = (row < N_HALF) ? src + (size_t)row * D
                                    : tgt + (size_t)(row - N_HALF) * D;
    float4 v0 = ((const float4*)(X + k0))[0];
    float4 v1 = ((const float4*)(X + k0))[1];
    float vs[8] = {v0.x, v0.y, v0.z, v0.w, v1.x, v1.y, v1.z, v1.w};
    half8 h;
    float p = 0.f;
#pragma unroll
    for (int e = 0; e < 8; ++e) {
        h[e] = (_Float16)vs[e];  // RNE
        p += vs[e] * vs[e];
    }
    ((half8*)Fh)[tid] = h;
#pragma unroll
    for (int e = 0; e < 8; ++e) atomicAdd(&cs[k0 + e], vs[e]);  // LDS only
    // lanes l, l+16, l+32, l+48 share (row, s-half)
    p += __shfl_down(p, 32, 64);
    p += __shfl_down(p, 16, 64);
    int w = t >> 6;
    if (l < 16) hn[w][l] = p;
    __syncthreads();
    if (t < 64) {
        float nr = 0.f;
        int tile = t >> 4, r = t & 15;
        if (t < 32) {
            nr = hn[tile * 2][r] + hn[tile * 2 + 1][r];
            g_norms[(blockIdx.x * 2 + tile) * 16 + r] = nr;
        }
        nr += __shfl_down(nr, 32, 64);
        nr += __shfl_down(nr, 16, 64);
        nr += __shfl_down(nr, 8, 64);
        nr += __shfl_down(nr, 4, 64);
        nr += __shfl_down(nr, 2, 64);
        nr += __shfl_down(nr, 1, 64);
        if (t == 0) g_pssq[blockIdx.x] = nr;
    }
    if (t < D) g_pcol[blockIdx.x * D + t] = cs[t];
}

// Bandwidth coefficient, one small block.
__global__ __launch_bounds__(256) void mmd_bw() {
    __shared__ float scol[4][64];
    __shared__ float sssq[4];
    int t = threadIdx.x, w = t >> 6, l = t & 63;
    float csum = 0.f;
#pragma unroll 16
    for (int q = 0; q < 64; ++q) csum += g_pcol[(w * 64 + q) * 64 + l];
    float sq = g_pssq[w * 64 + l];
#pragma unroll
    for (int off = 32; off; off >>= 1) sq += __shfl_xor(sq, off, 64);
    scol[w][l] = csum;
    if (l == 0) sssq[w] = sq;
    __syncthreads();
    if (t < 64) {
        float colsum = (scol[0][l] + scol[1][l]) + (scol[2][l] + scol[3][l]);
        float s2 = colsum * colsum;
#pragma unroll
        for (int off = 32; off; off >>= 1) s2 += __shfl_xor(s2, off, 64);
        if (t == 0) {
            float ssq = (sssq[0] + sssq[1]) + (sssq[2] + sssq[3]);
            const float M = (float)M_TOT;
            float sumL2 = 2.f * M * ssq - 2.f * s2;
            float bwq = sumL2 / (M * M - M) * 0.25f;  // / KERNEL_MUL^2
            g_coef = -1.4426950408889634f / (bwq * 16.f);
        }
    }
}

static __device__ inline void decode_pair(int id, int& bi, int& bj) {
    bi = (int)(64.5f - sqrtf(4160.25f - 2.0f * (float)id));
    while ((64 * (bi + 1) - ((bi + 1) * bi) / 2) <= id) ++bi;
    while ((64 * bi - (bi * (bi - 1)) / 2) > id) --bi;
    bj = bi + (id - (64 * bi - (bi * (bi - 1)) / 2));
}

// Main: one 128x128 pair tile per block, 8 waves of 64x32 each.
// fp16 single-MFMA per 16x16 k-step (vs bf16 hi/lo double): half the
// fragment loads (12 x 16B per wave) and half the MFMA count of R8.
// Epilogue: 1 exp2 + 4 squarings, 4-way striped accumulators (R8 form).
__global__ __launch_bounds__(512) void mmd_main() {
    __shared__ float sred[8];
    int t = threadIdx.x, w = t >> 6, l = t & 63;
    int wr = w >> 2, wc = w & 3;  // 2x4 wave grid: 64 rows x 32 cols per wave
    float g0 = g_coef;
    float c2 = -2.f * g0;
    const half8* FH = (const half8*)Fh;

    int bi, bj;
    decode_pair(blockIdx.x, bi, bj);

    // Norm loads issued early (consumed in epilogue).
    float nas[4][4];
#pragma unroll
    for (int m = 0; m < 4; ++m) {
        float4 v = *(const float4*)&g_norms[bi * 128 + wr * 64 + m * 16 + (l >> 4) * 4];
        nas[m][0] = v.x * g0; nas[m][1] = v.y * g0;
        nas[m][2] = v.z * g0; nas[m][3] = v.w * g0;
    }
    float nbv[2];
#pragma unroll
    for (int n = 0; n < 2; ++n)
        nbv[n] = g_norms[bj * 128 + wc * 32 + n * 16 + (l & 15)] * g0;

    f32x4 acc[4][2] = {};
#pragma unroll
    for (int s = 0; s < 2; ++s) {
        half8 bh[2];
#pragma unroll
        for (int n = 0; n < 2; ++n)
            bh[n] = FH[((bj * 8 + wc * 2 + n) * 2 + s) * 64 + l];
#pragma unroll
        for (int m = 0; m < 4; ++m) {
            half8 ah = FH[((bi * 8 + wr * 4 + m) * 2 + s) * 64 + l];
#pragma unroll
            for (int n = 0; n < 2; ++n)
                acc[m][n] = __builtin_amdgcn_mfma_f32_16x16x32_f16(ah, bh[n], acc[m][n], 0, 0, 0);
        }
    }

    // Epilogue: K_sum over 5 bandwidths via 1 exp2 + 4 squarings.
    float part4[4] = {0.f, 0.f, 0.f, 0.f};
#pragma unroll
    for (int m = 0; m < 4; ++m)
#pragma unroll
        for (int n = 0; n < 2; ++n)
#pragma unroll
            for (int r = 0; r < 4; ++r) {
                float t0 = fmaf(acc[m][n][r], c2, nas[m][r] + nbv[n]);
                float k4 = __builtin_amdgcn_exp2f(t0);
                float k3 = k4 * k4;
                float k2 = k3 * k3;
                float k1 = k2 * k2;
                float k0 = k1 * k1;
                part4[r] += (k4 + k3) + ((k2 + k1) + k0);
            }
    float part = (part4[0] + part4[1]) + (part4[2] + part4[3]);

#pragma unroll
    for (int off = 32; off; off >>= 1) part += __shfl_down(part, off, 64);
    if (l == 0) sred[w] = part;
    __syncthreads();
    if (t == 0) {
        float tot = ((sred[0] + sred[1]) + (sred[2] + sred[3])) +
                    ((sred[4] + sred[5]) + (sred[6] + sred[7]));
        float sgn = ((bi < 32) == (bj < 32)) ? 1.f : -1.f;
        float scl = (bi == bj) ? 1.f : 2.f;
        g_part[blockIdx.x] = (double)tot * (double)(sgn * scl);
    }
}

// Deterministic tree reduce of the 2080 per-pair doubles.
__global__ __launch_bounds__(256) void mmd_out(float* __restrict__ out) {
    __shared__ double wred[4];
    int t = threadIdx.x;
    double s = 0.0;
    for (int i = t; i < NPAIR; i += 256) s += g_part[i];
#pragma unroll
    for (int off = 32; off; off >>= 1) s += __shfl_down(s, off, 64);
    if ((t & 63) == 0) wred[t >> 6] = s;
    __syncthreads();
    if (t == 0)
        out[0] = (float)((wred[0] + wred[1] + wred[2] + wred[3]) * (1.0 / 16777216.0));
}

extern "C" void kernel_launch(void* const* d_in, const int* in_sizes, int n_in,
                              void* d_out, int out_size, void* d_ws, size_t ws_size,
                              hipStream_t stream) {
    const float* src = (const float*)d_in[0];
    const float* tgt = (const float*)d_in[1];
    float* out = (float*)d_out;

    mmd_prep<<<256, 256, 0, stream>>>(src, tgt);
    mmd_bw<<<1, 256, 0, stream>>>();
    mmd_main<<<NPAIR, 512, 0, stream>>>();
    mmd_out<<<1, 256, 0, stream>>>(out);
}